// Round 9
// baseline (349.937 us; speedup 1.0000x reference)
//
#include <hip/hip_runtime.h>

typedef __attribute__((ext_vector_type(8))) short          bf16x8;
typedef __attribute__((ext_vector_type(8))) unsigned short u16x8;
typedef __attribute__((ext_vector_type(4))) unsigned short u16x4;
typedef __attribute__((ext_vector_type(4))) float          f32x4;
typedef __attribute__((ext_vector_type(4))) int            i32x4;
typedef __attribute__((ext_vector_type(4))) unsigned int   u32x4;

union U8 { u16x8 u; bf16x8 b; u32x4 w; };
union U4 { u16x4 u; unsigned w[2]; };

__device__ __forceinline__ unsigned short f2bf(float f){
  unsigned u = __float_as_uint(f);
  return (unsigned short)((u + 0x7fffu + ((u >> 16) & 1u)) >> 16);
}
// pack two floats to bf16x2 (round-half-up): lo->low16, hi->high16. exact 0 preserved.
__device__ __forceinline__ unsigned pack_bf16(float lo, float hi){
  unsigned a = __float_as_uint(hi) + 0x8000u;
  unsigned b = __float_as_uint(lo) + 0x8000u;
  return __builtin_amdgcn_perm(a, b, 0x07060302u);
}

#define NN  1024
#define FIN 256
#define NH  8
#define FO  64

// ---------------------------------------------------------------------------
// Stage 0: wfrag = w in MFMA-B-frag layout; Abits = bit-packed A;
//          out = bias*mz (pre-init for 8-way head merge via atomics).
// ---------------------------------------------------------------------------
__global__ __launch_bounds__(256) void stage0(
    const float* __restrict__ w, const int* __restrict__ A,
    const float* __restrict__ bias, const float* __restrict__ mz,
    unsigned short* __restrict__ wfrag, unsigned long long* __restrict__ Abits,
    float* __restrict__ out)
{
  const int tid = blockIdx.x * 256 + threadIdx.x;    // 262144 threads
  if (tid < 16384){
    const int lane = tid & 63, ss = (tid >> 6) & 3, kc = (tid >> 8) & 7, h = tid >> 11;
    const int o = 16 * ss + (lane & 15);
    const int f = kc * 32 + (lane >> 4) * 8;
    u16x8 r;
    #pragma unroll
    for (int j = 0; j < 8; j++) r[j] = f2bf(w[(h * FIN + f + j) * FO + o]);
    *(u16x8*)(wfrag + tid * 8) = r;
  }
  #pragma unroll
  for (int k = 0; k < 2; k++){                       // out = bias*mz
    const int i = tid + k * 262144;
    out[i] = bias[i & 63] * mz[i >> 6];
  }
  for (int i = tid; i < 8388608; i += 262144){       // adjacency bit-pack
    unsigned long long m = __ballot(A[i] > 0);
    if ((threadIdx.x & 63) == 0) Abits[i >> 6] = m;
  }
}

// ---------------------------------------------------------------------------
// Stage A: recx built in LDS per 16-row tile; h = recx @ w (MFMA);
// panel stores hT[b,h,mtile,o,32] + exp tables e^s, e^.2s, e^d, e^.2d.
// grid (64 tiles(16 rows), 8 b) = 512 blocks, block 512 (8 waves = 8 heads).
// ---------------------------------------------------------------------------
__global__ __launch_bounds__(512, 4) void stageA(
    const float* __restrict__ x, const float* __restrict__ e_at,
    const float* __restrict__ Np, const unsigned short* __restrict__ wfrag,
    const float* __restrict__ a_src, const float* __restrict__ a_dst,
    unsigned short* __restrict__ hT,
    float* __restrict__ exps, float* __restrict__ exps2,
    float* __restrict__ expd, float* __restrict__ expd2)
{
  __shared__ unsigned short rex[16 * 264];   // 16 rows x 256 f, pad 264
  const int t = threadIdx.x;
  const int n0 = blockIdx.x * 16, b = blockIdx.y;

  {                                          // cooperative recx tile build
    const int row = t >> 5, f0 = (t & 31) * 8;
    const int nrow = n0 + row;
    const float* ep = e_at + (b * NN + nrow) * FIN + f0;
    const float* qp = Np + nrow * FIN + f0;
    const float* xp = x + b * FIN + f0;
    f32x4 e0 = *(const f32x4*)ep, e1 = *(const f32x4*)(ep + 4);
    f32x4 q0 = *(const f32x4*)qp, q1 = *(const f32x4*)(qp + 4);
    f32x4 x0 = *(const f32x4*)xp, x1 = *(const f32x4*)(xp + 4);
    u16x8 r;
    #pragma unroll
    for (int j = 0; j < 4; j++){
      r[j]     = f2bf(e0[j] * q0[j] * x0[j]);
      r[j + 4] = f2bf(e1[j] * q1[j] * x1[j]);
    }
    *(u16x8*)(rex + row * 264 + f0) = r;
  }
  __syncthreads();

  const int h = t >> 6, lane = t & 63, quad = lane >> 4, l15 = lane & 15;
  const unsigned short* wf = wfrag + h * 16384 + lane * 8;

  f32x4 acc[4] = {};
  #pragma unroll
  for (int kc = 0; kc < 8; kc++){
    U8 a0, bf[4];
    a0.u = *(const u16x8*)(rex + l15 * 264 + kc * 32 + quad * 8);
    #pragma unroll
    for (int ss = 0; ss < 4; ss++) bf[ss].u = *(const u16x8*)(wf + (kc * 4 + ss) * 512);
    #pragma unroll
    for (int ss = 0; ss < 4; ss++)
      acc[ss] = __builtin_amdgcn_mfma_f32_16x16x32_bf16(a0.b, bf[ss].b, acc[ss], 0, 0, 0);
  }

  // panel store: [b,h,mtile,o(64),m(32)], C/D row(n)=quad*4+i, col(o)=16ss+l15
  {
    const int mtile = blockIdx.x >> 1, moff = (blockIdx.x & 1) * 16;
    unsigned short* pan = hT + (size_t)(((b * NH + h) * 32 + mtile) * 64) * 32;
    #pragma unroll
    for (int ss = 0; ss < 4; ss++){
      U4 v;
      v.w[0] = pack_bf16(acc[ss][0], acc[ss][1]);
      v.w[1] = pack_bf16(acc[ss][2], acc[ss][3]);
      *(u16x4*)(pan + (16 * ss + l15) * 32 + moff + quad * 4) = v.u;
    }
  }

  // s/d reductions -> exp tables
  float as4[4], ad4[4];
  #pragma unroll
  for (int ss = 0; ss < 4; ss++){
    as4[ss] = a_src[h * FO + 16 * ss + l15];
    ad4[ss] = a_dst[h * FO + 16 * ss + l15];
  }
  #pragma unroll
  for (int i = 0; i < 4; i++){
    float ps = 0.f, pd = 0.f;
    #pragma unroll
    for (int ss = 0; ss < 4; ss++){ ps += acc[ss][i] * as4[ss]; pd += acc[ss][i] * ad4[ss]; }
    #pragma unroll
    for (int off = 1; off < 16; off <<= 1){
      ps += __shfl_xor(ps, off);
      pd += __shfl_xor(pd, off);
    }
    if (l15 == 0){
      const int idx = (b * NH + h) * NN + n0 + quad * 4 + i;
      exps [idx] = __expf(ps);
      exps2[idx] = __expf(0.2f * ps);
      expd [idx] = __expf(pd);
      expd2[idx] = __expf(0.2f * pd);
    }
  }
}

// ---------------------------------------------------------------------------
// Phase B: fused masked-softmax aggregation.
// grid (16 tiles(64 rows), 8 h, 8 b) = 1024 blocks, block 512 (8 waves).
// Wave = all 64 rows x 128 m (4 chunks): panel read ONCE per block (hT traffic
// 128 MB total). l computed in-block; LDS oacc merges 8 waves; ONE global
// atomicAdd per out element per block (8-way head merge, out pre-inited).
// ---------------------------------------------------------------------------
__global__ __launch_bounds__(512, 4) void phaseB(
    const unsigned* __restrict__ Aw,
    const unsigned short* __restrict__ hT,
    const float* __restrict__ exps, const float* __restrict__ exps2,
    const float* __restrict__ expd, const float* __restrict__ expd2,
    const float* __restrict__ mz, float* __restrict__ out)
{
  __shared__ float ed_l[NN];             // 4 KB  e^d
  __shared__ float e2_l[NN];             // 4 KB  e^{0.2d}
  __shared__ unsigned mask_l[64 * 33];   // 8.4 KB
  __shared__ float es_l[64], es2_l[64], sc_l[64], l_l[64];
  __shared__ float oacc[64 * 65];        // 16.6 KB
  const int t = threadIdx.x;
  const int n0 = blockIdx.x * 64, h = blockIdx.y, b = blockIdx.z;
  const int bh = b * NH + h;

  if (t < 256) *(f32x4*)(ed_l + t * 4)         = *(const f32x4*)(expd  + bh * NN + t * 4);
  else         *(f32x4*)(e2_l + (t - 256) * 4) = *(const f32x4*)(expd2 + bh * NN + (t - 256) * 4);
  #pragma unroll
  for (int k = 0; k < 4; k++){
    const int i = t + k * 512;
    mask_l[(i >> 5) * 33 + (i & 31)] = Aw[(b * NN + n0 + (i >> 5)) * 32 + (i & 31)];
  }
  if (t < 64)       es_l [t]       = exps [bh * NN + n0 + t];
  else if (t < 128) es2_l[t - 64]  = exps2[bh * NN + n0 + t - 64];
  else if (t < 192) sc_l [t - 128] = mz[b * NN + n0 + t - 128];
  else if (t < 256) l_l  [t - 192] = 0.f;
  for (int i = t; i < 64 * 65; i += 512) oacc[i] = 0.f;
  __syncthreads();

  const int wv = t >> 6, lane = t & 63, quad = lane >> 4, l15 = lane & 15;
  const unsigned short* pb = hT + (size_t)bh * 65536 + l15 * 32 + quad * 8;
  const int c0 = wv * 4;                 // this wave's 4 m-chunks

  float Es[4], Es2[4];
  #pragma unroll
  for (int rg = 0; rg < 4; rg++){
    Es[rg]  = es_l [rg * 16 + l15];
    Es2[rg] = es2_l[rg * 16 + l15];
  }

  U8 pan[2][4];
  #pragma unroll
  for (int ss = 0; ss < 4; ss++)
    pan[0][ss].u = *(const u16x8*)(pb + (size_t)c0 * 2048 + ss * 512);

  f32x4 acc[4][4] = {};
  float lp[4] = {0.f, 0.f, 0.f, 0.f};

  #pragma unroll
  for (int cc = 0; cc < 4; cc++){
    const int c = c0 + cc;
    if (cc + 1 < 4){                     // depth-2: next chunk's panel in flight
      #pragma unroll
      for (int ss = 0; ss < 4; ss++)
        pan[(cc + 1) & 1][ss].u = *(const u16x8*)(pb + (size_t)(c + 1) * 2048 + ss * 512);
    }
    f32x4 dv0 = *(const f32x4*)(ed_l + c * 32 + quad * 8);
    f32x4 dv1 = *(const f32x4*)(ed_l + c * 32 + quad * 8 + 4);
    f32x4 gv0 = *(const f32x4*)(e2_l + c * 32 + quad * 8);
    f32x4 gv1 = *(const f32x4*)(e2_l + c * 32 + quad * 8 + 4);
    #pragma unroll
    for (int rg = 0; rg < 4; rg++){
      const unsigned ab = mask_l[(rg * 16 + l15) * 33 + c] >> (quad * 8);
      float pv[8];
      #pragma unroll
      for (int j = 0; j < 8; j++){
        const float d = (j < 4) ? dv0[j] : dv1[j - 4];
        const float g = (j < 4) ? gv0[j] : gv1[j - 4];
        const float e = fmaxf(Es[rg] * d, Es2[rg] * g);
        pv[j] = (ab & (1u << j)) ? e : 0.f;
      }
      lp[rg] += ((pv[0] + pv[1]) + (pv[2] + pv[3])) + ((pv[4] + pv[5]) + (pv[6] + pv[7]));
      U8 p;
      #pragma unroll
      for (int r = 0; r < 4; r++) p.w[r] = pack_bf16(pv[2 * r], pv[2 * r + 1]);
      #pragma unroll
      for (int ss = 0; ss < 4; ss++)
        acc[rg][ss] = __builtin_amdgcn_mfma_f32_16x16x32_bf16(p.b, pan[cc & 1][ss].b, acc[rg][ss], 0, 0, 0);
    }
  }

  // merge row-sum partials (each wave covered 128 of 1024 m)
  #pragma unroll
  for (int rg = 0; rg < 4; rg++){
    lp[rg] += __shfl_xor(lp[rg], 16);
    lp[rg] += __shfl_xor(lp[rg], 32);
  }
  if (lane < 16){
    #pragma unroll
    for (int rg = 0; rg < 4; rg++)
      atomicAdd(&l_l[rg * 16 + lane], lp[rg]);
  }
  __syncthreads();

  // scale (0.125 * mz / l) and merge 8 waves' partial aggregates in LDS
  #pragma unroll
  for (int rg = 0; rg < 4; rg++){
    float s[4];
    #pragma unroll
    for (int i = 0; i < 4; i++){
      const int row = rg * 16 + quad * 4 + i;
      s[i] = 0.125f * sc_l[row] / l_l[row];
    }
    #pragma unroll
    for (int ss = 0; ss < 4; ss++)
      #pragma unroll
      for (int i = 0; i < 4; i++)
        atomicAdd(&oacc[(rg * 16 + quad * 4 + i) * 65 + ss * 16 + l15], acc[rg][ss][i] * s[i]);
  }
  __syncthreads();

  // one global atomic per out element per block (8-way head merge)
  for (int i = t; i < 4096; i += 512){
    const int r = i >> 6, o = i & 63;
    atomicAdd(out + (size_t)(b * NN + n0 + r) * FO + o, oacc[r * 65 + o]);
  }
}

extern "C" void kernel_launch(void* const* d_in, const int* in_sizes, int n_in,
                              void* d_out, int out_size, void* d_ws, size_t ws_size,
                              hipStream_t stream)
{
  (void)in_sizes; (void)n_in; (void)out_size; (void)ws_size;
  const float* x    = (const float*)d_in[0];
  const int*   A    = (const int*)d_in[1];
  const float* mz   = (const float*)d_in[2];
  const float* e_at = (const float*)d_in[4];
  const float* Np   = (const float*)d_in[5];
  const float* w    = (const float*)d_in[6];
  const float* asrc = (const float*)d_in[7];
  const float* adst = (const float*)d_in[8];
  const float* bias = (const float*)d_in[9];
  float* out = (float*)d_out;

  char* ws = (char*)d_ws;
  unsigned short* wfrag = (unsigned short*)ws;                     // 256 KB
  unsigned short* hT    = (unsigned short*)(ws + 262144);          // 8 MB
  float* exps  = (float*)(ws + 8650752);                           // 256 KB
  float* exps2 = (float*)(ws + 8912896);                           // 256 KB
  float* expd  = (float*)(ws + 9175040);                           // 256 KB
  float* expd2 = (float*)(ws + 9437184);                           // 256 KB
  unsigned long long* Abits = (unsigned long long*)(ws + 9699328); // 1 MB

  stage0<<<dim3(1024), dim3(256), 0, stream>>>(w, A, bias, mz, wfrag, Abits, out);
  stageA<<<dim3(64, 8), dim3(512), 0, stream>>>(x, e_at, Np, wfrag, asrc, adst,
                                                hT, exps, exps2, expd, expd2);
  phaseB<<<dim3(16, 8, 8), dim3(512), 0, stream>>>((const unsigned*)Abits, hT,
                                                   exps, exps2, expd, expd2,
                                                   mz, out);
}

// Round 10
// 232.955 us; speedup vs baseline: 1.5022x; 1.5022x over previous
//
#include <hip/hip_runtime.h>

typedef __attribute__((ext_vector_type(8))) short          bf16x8;
typedef __attribute__((ext_vector_type(8))) unsigned short u16x8;
typedef __attribute__((ext_vector_type(4))) unsigned short u16x4;
typedef __attribute__((ext_vector_type(4))) float          f32x4;
typedef __attribute__((ext_vector_type(4))) int            i32x4;
typedef __attribute__((ext_vector_type(4))) unsigned int   u32x4;

union U8 { u16x8 u; bf16x8 b; u32x4 w; };
union U4 { u16x4 u; unsigned w[2]; };

__device__ __forceinline__ unsigned short f2bf(float f){
  unsigned u = __float_as_uint(f);
  return (unsigned short)((u + 0x7fffu + ((u >> 16) & 1u)) >> 16);
}
// pack two floats to bf16x2 (round-half-up): lo->low16, hi->high16. exact 0 preserved.
__device__ __forceinline__ unsigned pack_bf16(float lo, float hi){
  unsigned a = __float_as_uint(hi) + 0x8000u;
  unsigned b = __float_as_uint(lo) + 0x8000u;
  return __builtin_amdgcn_perm(a, b, 0x07060302u);
}

#define NN  1024
#define FIN 256
#define NH  8
#define FO  64

// ---------------------------------------------------------------------------
// Stage 0: wfrag = w in MFMA-B-frag layout; Abits = bit-packed A;
//          out = bias*mz (pre-init for 8-way head merge via atomics).
// ---------------------------------------------------------------------------
__global__ __launch_bounds__(256) void stage0(
    const float* __restrict__ w, const int* __restrict__ A,
    const float* __restrict__ bias, const float* __restrict__ mz,
    unsigned short* __restrict__ wfrag, unsigned long long* __restrict__ Abits,
    float* __restrict__ out)
{
  const int tid = blockIdx.x * 256 + threadIdx.x;    // 262144 threads
  if (tid < 16384){
    const int lane = tid & 63, ss = (tid >> 6) & 3, kc = (tid >> 8) & 7, h = tid >> 11;
    const int o = 16 * ss + (lane & 15);
    const int f = kc * 32 + (lane >> 4) * 8;
    u16x8 r;
    #pragma unroll
    for (int j = 0; j < 8; j++) r[j] = f2bf(w[(h * FIN + f + j) * FO + o]);
    *(u16x8*)(wfrag + tid * 8) = r;
  }
  #pragma unroll
  for (int k = 0; k < 2; k++){                       // out = bias*mz
    const int i = tid + k * 262144;
    out[i] = bias[i & 63] * mz[i >> 6];
  }
  for (int i = tid; i < 8388608; i += 262144){       // adjacency bit-pack
    unsigned long long m = __ballot(A[i] > 0);
    if ((threadIdx.x & 63) == 0) Abits[i >> 6] = m;
  }
}

// ---------------------------------------------------------------------------
// Stage A: recx built in LDS per 16-row tile; h = recx @ w (MFMA);
// panel stores hT[b,h,mtile,o,32] + exp tables e^s, e^.2s, e^d, e^.2d.
// grid (64 tiles(16 rows), 8 b) = 512 blocks, block 512 (8 waves = 8 heads).
// ---------------------------------------------------------------------------
__global__ __launch_bounds__(512, 4) void stageA(
    const float* __restrict__ x, const float* __restrict__ e_at,
    const float* __restrict__ Np, const unsigned short* __restrict__ wfrag,
    const float* __restrict__ a_src, const float* __restrict__ a_dst,
    unsigned short* __restrict__ hT,
    float* __restrict__ exps, float* __restrict__ exps2,
    float* __restrict__ expd, float* __restrict__ expd2)
{
  __shared__ unsigned short rex[16 * 264];   // 16 rows x 256 f, pad 264
  const int t = threadIdx.x;
  const int n0 = blockIdx.x * 16, b = blockIdx.y;

  {                                          // cooperative recx tile build
    const int row = t >> 5, f0 = (t & 31) * 8;
    const int nrow = n0 + row;
    const float* ep = e_at + (b * NN + nrow) * FIN + f0;
    const float* qp = Np + nrow * FIN + f0;
    const float* xp = x + b * FIN + f0;
    f32x4 e0 = *(const f32x4*)ep, e1 = *(const f32x4*)(ep + 4);
    f32x4 q0 = *(const f32x4*)qp, q1 = *(const f32x4*)(qp + 4);
    f32x4 x0 = *(const f32x4*)xp, x1 = *(const f32x4*)(xp + 4);
    u16x8 r;
    #pragma unroll
    for (int j = 0; j < 4; j++){
      r[j]     = f2bf(e0[j] * q0[j] * x0[j]);
      r[j + 4] = f2bf(e1[j] * q1[j] * x1[j]);
    }
    *(u16x8*)(rex + row * 264 + f0) = r;
  }
  __syncthreads();

  const int h = t >> 6, lane = t & 63, quad = lane >> 4, l15 = lane & 15;
  const unsigned short* wf = wfrag + h * 16384 + lane * 8;

  f32x4 acc[4] = {};
  #pragma unroll
  for (int kc = 0; kc < 8; kc++){
    U8 a0, bf[4];
    a0.u = *(const u16x8*)(rex + l15 * 264 + kc * 32 + quad * 8);
    #pragma unroll
    for (int ss = 0; ss < 4; ss++) bf[ss].u = *(const u16x8*)(wf + (kc * 4 + ss) * 512);
    #pragma unroll
    for (int ss = 0; ss < 4; ss++)
      acc[ss] = __builtin_amdgcn_mfma_f32_16x16x32_bf16(a0.b, bf[ss].b, acc[ss], 0, 0, 0);
  }

  // panel store: [b,h,mtile,o(64),m(32)], C/D row(n)=quad*4+i, col(o)=16ss+l15
  {
    const int mtile = blockIdx.x >> 1, moff = (blockIdx.x & 1) * 16;
    unsigned short* pan = hT + (size_t)(((b * NH + h) * 32 + mtile) * 64) * 32;
    #pragma unroll
    for (int ss = 0; ss < 4; ss++){
      U4 v;
      v.w[0] = pack_bf16(acc[ss][0], acc[ss][1]);
      v.w[1] = pack_bf16(acc[ss][2], acc[ss][3]);
      *(u16x4*)(pan + (16 * ss + l15) * 32 + moff + quad * 4) = v.u;
    }
  }

  // s/d reductions -> exp tables
  float as4[4], ad4[4];
  #pragma unroll
  for (int ss = 0; ss < 4; ss++){
    as4[ss] = a_src[h * FO + 16 * ss + l15];
    ad4[ss] = a_dst[h * FO + 16 * ss + l15];
  }
  #pragma unroll
  for (int i = 0; i < 4; i++){
    float ps = 0.f, pd = 0.f;
    #pragma unroll
    for (int ss = 0; ss < 4; ss++){ ps += acc[ss][i] * as4[ss]; pd += acc[ss][i] * ad4[ss]; }
    #pragma unroll
    for (int off = 1; off < 16; off <<= 1){
      ps += __shfl_xor(ps, off);
      pd += __shfl_xor(pd, off);
    }
    if (l15 == 0){
      const int idx = (b * NH + h) * NN + n0 + quad * 4 + i;
      exps [idx] = __expf(ps);
      exps2[idx] = __expf(0.2f * ps);
      expd [idx] = __expf(pd);
      expd2[idx] = __expf(0.2f * pd);
    }
  }
}

// ---------------------------------------------------------------------------
// Phase B: fused masked-softmax aggregation.
// grid (16 tiles(64 rows), 8 h, 8 b) = 1024 blocks, block 512 (8 waves),
// 4 blocks/CU. Wave = all 64 rows x 32 o (og half) x 256 m (mq quarter):
// acc[4][2] = 32 AGPRs (no spills); the two og waves read DISJOINT panel
// halves -> each block reads its (b,h) panel exactly once (128 MB total,
// L2-local since 16 consecutive blocks share a panel). l in-block; LDS oacc
// merges 8 waves; one global atomicAdd per out element per block.
// ---------------------------------------------------------------------------
__global__ __launch_bounds__(512, 4) void phaseB(
    const unsigned* __restrict__ Aw,
    const unsigned short* __restrict__ hT,
    const float* __restrict__ exps, const float* __restrict__ exps2,
    const float* __restrict__ expd, const float* __restrict__ expd2,
    const float* __restrict__ mz, float* __restrict__ out)
{
  __shared__ float ed_l[NN];             // 4 KB  e^d
  __shared__ float e2_l[NN];             // 4 KB  e^{0.2d}
  __shared__ unsigned mask_l[64 * 33];   // 8.4 KB
  __shared__ float es_l[64], es2_l[64], sc_l[64], l_l[64];
  __shared__ float oacc[64 * 65];        // 16.6 KB
  const int t = threadIdx.x;
  const int n0 = blockIdx.x * 64, h = blockIdx.y, b = blockIdx.z;
  const int bh = b * NH + h;

  if (t < 256) *(f32x4*)(ed_l + t * 4)         = *(const f32x4*)(expd  + bh * NN + t * 4);
  else         *(f32x4*)(e2_l + (t - 256) * 4) = *(const f32x4*)(expd2 + bh * NN + (t - 256) * 4);
  #pragma unroll
  for (int k = 0; k < 4; k++){
    const int i = t + k * 512;
    mask_l[(i >> 5) * 33 + (i & 31)] = Aw[(b * NN + n0 + (i >> 5)) * 32 + (i & 31)];
  }
  if (t < 64)       es_l [t]       = exps [bh * NN + n0 + t];
  else if (t < 128) es2_l[t - 64]  = exps2[bh * NN + n0 + t - 64];
  else if (t < 192) sc_l [t - 128] = mz[b * NN + n0 + t - 128];
  else if (t < 256) l_l  [t - 192] = 0.f;
  for (int i = t; i < 64 * 65; i += 512) oacc[i] = 0.f;
  __syncthreads();

  const int wv = t >> 6, lane = t & 63, quad = lane >> 4, l15 = lane & 15;
  const int og = wv & 1, mq = wv >> 1;   // o-half, m-quarter
  const int c0 = mq * 8;                 // 8 chunks of 32 m
  const unsigned short* pb = hT + (size_t)bh * 65536 + (size_t)(og * 2) * 512
                                + l15 * 32 + quad * 8;

  float Es[4], Es2[4];
  #pragma unroll
  for (int rg = 0; rg < 4; rg++){
    Es[rg]  = es_l [rg * 16 + l15];
    Es2[rg] = es2_l[rg * 16 + l15];
  }

  U8 pan[2][2];                          // depth-2 x 2 o-frags
  #pragma unroll
  for (int s = 0; s < 2; s++)
    pan[0][s].u = *(const u16x8*)(pb + (size_t)c0 * 2048 + s * 512);

  f32x4 acc[4][2] = {};
  float lp[4] = {0.f, 0.f, 0.f, 0.f};

  #pragma unroll
  for (int cc = 0; cc < 8; cc++){
    const int c = c0 + cc;
    if (cc + 1 < 8){                     // depth-2: next chunk's panel in flight
      #pragma unroll
      for (int s = 0; s < 2; s++)
        pan[(cc + 1) & 1][s].u = *(const u16x8*)(pb + (size_t)(c + 1) * 2048 + s * 512);
    }
    f32x4 dv0 = *(const f32x4*)(ed_l + c * 32 + quad * 8);
    f32x4 dv1 = *(const f32x4*)(ed_l + c * 32 + quad * 8 + 4);
    f32x4 gv0 = *(const f32x4*)(e2_l + c * 32 + quad * 8);
    f32x4 gv1 = *(const f32x4*)(e2_l + c * 32 + quad * 8 + 4);
    #pragma unroll
    for (int rg = 0; rg < 4; rg++){
      const unsigned ab = mask_l[(rg * 16 + l15) * 33 + c] >> (quad * 8);
      float pv[8];
      #pragma unroll
      for (int j = 0; j < 8; j++){
        const float d = (j < 4) ? dv0[j] : dv1[j - 4];
        const float g = (j < 4) ? gv0[j] : gv1[j - 4];
        const float e = fmaxf(Es[rg] * d, Es2[rg] * g);
        pv[j] = (ab & (1u << j)) ? e : 0.f;
      }
      lp[rg] += ((pv[0] + pv[1]) + (pv[2] + pv[3])) + ((pv[4] + pv[5]) + (pv[6] + pv[7]));
      U8 p;
      #pragma unroll
      for (int r = 0; r < 4; r++) p.w[r] = pack_bf16(pv[2 * r], pv[2 * r + 1]);
      #pragma unroll
      for (int s = 0; s < 2; s++)
        acc[rg][s] = __builtin_amdgcn_mfma_f32_16x16x32_bf16(p.b, pan[cc & 1][s].b, acc[rg][s], 0, 0, 0);
    }
  }

  // merge row-sum partials; only og=0 waves contribute (og=1 computed same P)
  #pragma unroll
  for (int rg = 0; rg < 4; rg++){
    lp[rg] += __shfl_xor(lp[rg], 16);
    lp[rg] += __shfl_xor(lp[rg], 32);
  }
  if (og == 0 && lane < 16){
    #pragma unroll
    for (int rg = 0; rg < 4; rg++)
      atomicAdd(&l_l[rg * 16 + lane], lp[rg]);
  }
  __syncthreads();

  // scale (0.125 * mz / l) and merge 8 waves' partial aggregates in LDS
  #pragma unroll
  for (int rg = 0; rg < 4; rg++){
    float s4[4];
    #pragma unroll
    for (int i = 0; i < 4; i++){
      const int row = rg * 16 + quad * 4 + i;
      s4[i] = 0.125f * sc_l[row] / l_l[row];
    }
    #pragma unroll
    for (int s = 0; s < 2; s++)
      #pragma unroll
      for (int i = 0; i < 4; i++)
        atomicAdd(&oacc[(rg * 16 + quad * 4 + i) * 65 + (og * 2 + s) * 16 + l15],
                  acc[rg][s][i] * s4[i]);
  }
  __syncthreads();

  // one global atomic per out element per block (8-way head merge)
  for (int i = t; i < 4096; i += 512){
    const int r = i >> 6, o = i & 63;
    atomicAdd(out + (size_t)(b * NN + n0 + r) * FO + o, oacc[r * 65 + o]);
  }
}

extern "C" void kernel_launch(void* const* d_in, const int* in_sizes, int n_in,
                              void* d_out, int out_size, void* d_ws, size_t ws_size,
                              hipStream_t stream)
{
  (void)in_sizes; (void)n_in; (void)out_size; (void)ws_size;
  const float* x    = (const float*)d_in[0];
  const int*   A    = (const int*)d_in[1];
  const float* mz   = (const float*)d_in[2];
  const float* e_at = (const float*)d_in[4];
  const float* Np   = (const float*)d_in[5];
  const float* w    = (const float*)d_in[6];
  const float* asrc = (const float*)d_in[7];
  const float* adst = (const float*)d_in[8];
  const float* bias = (const float*)d_in[9];
  float* out = (float*)d_out;

  char* ws = (char*)d_ws;
  unsigned short* wfrag = (unsigned short*)ws;                     // 256 KB
  unsigned short* hT    = (unsigned short*)(ws + 262144);          // 8 MB
  float* exps  = (float*)(ws + 8650752);                           // 256 KB
  float* exps2 = (float*)(ws + 8912896);                           // 256 KB
  float* expd  = (float*)(ws + 9175040);                           // 256 KB
  float* expd2 = (float*)(ws + 9437184);                           // 256 KB
  unsigned long long* Abits = (unsigned long long*)(ws + 9699328); // 1 MB

  stage0<<<dim3(1024), dim3(256), 0, stream>>>(w, A, bias, mz, wfrag, Abits, out);
  stageA<<<dim3(64, 8), dim3(512), 0, stream>>>(x, e_at, Np, wfrag, asrc, adst,
                                                hT, exps, exps2, expd, expd2);
  phaseB<<<dim3(16, 8, 8), dim3(512), 0, stream>>>((const unsigned*)Abits, hT,
                                                   exps, exps2, expd, expd2,
                                                   mz, out);
}

// Round 11
// 170.691 us; speedup vs baseline: 2.0501x; 1.3648x over previous
//
#include <hip/hip_runtime.h>

typedef __attribute__((ext_vector_type(8))) short          bf16x8;
typedef __attribute__((ext_vector_type(8))) unsigned short u16x8;
typedef __attribute__((ext_vector_type(4))) unsigned short u16x4;
typedef __attribute__((ext_vector_type(4))) float          f32x4;
typedef __attribute__((ext_vector_type(4))) int            i32x4;
typedef __attribute__((ext_vector_type(4))) unsigned int   u32x4;

union U8 { u16x8 u; bf16x8 b; u32x4 w; };
union U4 { u16x4 u; unsigned w[2]; };

__device__ __forceinline__ unsigned short f2bf(float f){
  unsigned u = __float_as_uint(f);
  return (unsigned short)((u + 0x7fffu + ((u >> 16) & 1u)) >> 16);
}
// pack two floats to bf16x2 (round-half-up): lo->low16, hi->high16. exact 0 preserved.
__device__ __forceinline__ unsigned pack_bf16(float lo, float hi){
  unsigned a = __float_as_uint(hi) + 0x8000u;
  unsigned b = __float_as_uint(lo) + 0x8000u;
  return __builtin_amdgcn_perm(a, b, 0x07060302u);
}

#define NN  1024
#define FIN 256
#define NH  8
#define FO  64

// ---------------------------------------------------------------------------
// Stage 0: wfrag = w in MFMA-B-frag layout; Abits = bit-packed A;
//          out = bias*mz (pre-init for head-merge atomics).
// ---------------------------------------------------------------------------
__global__ __launch_bounds__(256) void stage0(
    const float* __restrict__ w, const int* __restrict__ A,
    const float* __restrict__ bias, const float* __restrict__ mz,
    unsigned short* __restrict__ wfrag, unsigned long long* __restrict__ Abits,
    float* __restrict__ out)
{
  const int tid = blockIdx.x * 256 + threadIdx.x;    // 262144 threads
  if (tid < 16384){
    const int lane = tid & 63, ss = (tid >> 6) & 3, kc = (tid >> 8) & 7, h = tid >> 11;
    const int o = 16 * ss + (lane & 15);
    const int f = kc * 32 + (lane >> 4) * 8;
    u16x8 r;
    #pragma unroll
    for (int j = 0; j < 8; j++) r[j] = f2bf(w[(h * FIN + f + j) * FO + o]);
    *(u16x8*)(wfrag + tid * 8) = r;
  }
  #pragma unroll
  for (int k = 0; k < 2; k++){                       // out = bias*mz
    const int i = tid + k * 262144;
    out[i] = bias[i & 63] * mz[i >> 6];
  }
  for (int i = tid; i < 8388608; i += 262144){       // adjacency bit-pack
    unsigned long long m = __ballot(A[i] > 0);
    if ((threadIdx.x & 63) == 0) Abits[i >> 6] = m;
  }
}

// ---------------------------------------------------------------------------
// Stage A: recx built in LDS per 16-row tile; h = recx @ w (MFMA);
// panel stores hT[b,h,mtile,o,32] + exp tables e^s, e^.2s, e^d, e^.2d.
// grid (64 tiles(16 rows), 8 b) = 512 blocks, block 512 (8 waves = 8 heads).
// ---------------------------------------------------------------------------
__global__ __launch_bounds__(512, 4) void stageA(
    const float* __restrict__ x, const float* __restrict__ e_at,
    const float* __restrict__ Np, const unsigned short* __restrict__ wfrag,
    const float* __restrict__ a_src, const float* __restrict__ a_dst,
    unsigned short* __restrict__ hT,
    float* __restrict__ exps, float* __restrict__ exps2,
    float* __restrict__ expd, float* __restrict__ expd2)
{
  __shared__ unsigned short rex[16 * 264];   // 16 rows x 256 f, pad 264
  const int t = threadIdx.x;
  const int n0 = blockIdx.x * 16, b = blockIdx.y;

  {                                          // cooperative recx tile build
    const int row = t >> 5, f0 = (t & 31) * 8;
    const int nrow = n0 + row;
    const float* ep = e_at + (b * NN + nrow) * FIN + f0;
    const float* qp = Np + nrow * FIN + f0;
    const float* xp = x + b * FIN + f0;
    f32x4 e0 = *(const f32x4*)ep, e1 = *(const f32x4*)(ep + 4);
    f32x4 q0 = *(const f32x4*)qp, q1 = *(const f32x4*)(qp + 4);
    f32x4 x0 = *(const f32x4*)xp, x1 = *(const f32x4*)(xp + 4);
    u16x8 r;
    #pragma unroll
    for (int j = 0; j < 4; j++){
      r[j]     = f2bf(e0[j] * q0[j] * x0[j]);
      r[j + 4] = f2bf(e1[j] * q1[j] * x1[j]);
    }
    *(u16x8*)(rex + row * 264 + f0) = r;
  }
  __syncthreads();

  const int h = t >> 6, lane = t & 63, quad = lane >> 4, l15 = lane & 15;
  const unsigned short* wf = wfrag + h * 16384 + lane * 8;

  f32x4 acc[4] = {};
  #pragma unroll
  for (int kc = 0; kc < 8; kc++){
    U8 a0, bf[4];
    a0.u = *(const u16x8*)(rex + l15 * 264 + kc * 32 + quad * 8);
    #pragma unroll
    for (int ss = 0; ss < 4; ss++) bf[ss].u = *(const u16x8*)(wf + (kc * 4 + ss) * 512);
    #pragma unroll
    for (int ss = 0; ss < 4; ss++)
      acc[ss] = __builtin_amdgcn_mfma_f32_16x16x32_bf16(a0.b, bf[ss].b, acc[ss], 0, 0, 0);
  }

  // panel store: [b,h,mtile,o(64),m(32)], C/D row(n)=quad*4+i, col(o)=16ss+l15
  {
    const int mtile = blockIdx.x >> 1, moff = (blockIdx.x & 1) * 16;
    unsigned short* pan = hT + (size_t)(((b * NH + h) * 32 + mtile) * 64) * 32;
    #pragma unroll
    for (int ss = 0; ss < 4; ss++){
      U4 v;
      v.w[0] = pack_bf16(acc[ss][0], acc[ss][1]);
      v.w[1] = pack_bf16(acc[ss][2], acc[ss][3]);
      *(u16x4*)(pan + (16 * ss + l15) * 32 + moff + quad * 4) = v.u;
    }
  }

  // s/d reductions -> exp tables
  float as4[4], ad4[4];
  #pragma unroll
  for (int ss = 0; ss < 4; ss++){
    as4[ss] = a_src[h * FO + 16 * ss + l15];
    ad4[ss] = a_dst[h * FO + 16 * ss + l15];
  }
  #pragma unroll
  for (int i = 0; i < 4; i++){
    float ps = 0.f, pd = 0.f;
    #pragma unroll
    for (int ss = 0; ss < 4; ss++){ ps += acc[ss][i] * as4[ss]; pd += acc[ss][i] * ad4[ss]; }
    #pragma unroll
    for (int off = 1; off < 16; off <<= 1){
      ps += __shfl_xor(ps, off);
      pd += __shfl_xor(pd, off);
    }
    if (l15 == 0){
      const int idx = (b * NH + h) * NN + n0 + quad * 4 + i;
      exps [idx] = __expf(ps);
      exps2[idx] = __expf(0.2f * ps);
      expd [idx] = __expf(pd);
      expd2[idx] = __expf(0.2f * pd);
    }
  }
}

// ---------------------------------------------------------------------------
// Stage B: fused masked-softmax aggregation (R7 structure, proven 58 us)
// + XCD-locality swizzle: the 32 row-tile blocks of one (b,head-pair) panel
// get block ids congruent mod 8 -> same XCD (round-robin heuristic) -> the
// panel stays in that XCD's 4 MB L2 (4 panels x 128 KB resident).
// grid 1024 linear, block 512 (8 waves = 2h x 2rg x 2mh). Head merge via
// global fp32 atomics into pre-initialized out.
// ---------------------------------------------------------------------------
__global__ __launch_bounds__(512, 8) void stageB(
    const unsigned* __restrict__ Aw,
    const unsigned short* __restrict__ hT,
    const float* __restrict__ exps, const float* __restrict__ exps2,
    const float* __restrict__ expd, const float* __restrict__ expd2,
    const float* __restrict__ mz, float* __restrict__ out)
{
  __shared__ float ed_l[2 * NN];         // 8 KB (2 heads)
  __shared__ float e2_l[2 * NN];         // 8 KB
  __shared__ unsigned mask_l[32 * 33];   // 4.2 KB
  __shared__ float l_l[4 * 16];          // (hl,rg) x 16 rows
  const int t = threadIdx.x;

  // ---- XCD swizzle: id = 8*(pp*32 + j) + xcd ;  panel p = pp*8+xcd ----
  const int id  = blockIdx.x;
  const int xcd = id & 7;
  const int rest = id >> 3;
  const int j   = rest & 31;             // row-tile 0..31
  const int p   = (rest >> 5) * 8 + xcd; // panel 0..31
  const int n0  = j * 32;
  const int hq  = p & 3;                 // head-pair 0..3
  const int b   = p >> 2;                // batch 0..7

  const int w = t >> 6, lane = t & 63, quad = lane >> 4, l15 = lane & 15;
  const int hl = w & 1, rg = (w >> 1) & 1, mh = w >> 2;
  const int h = hq * 2 + hl;

  if (t < 64) l_l[t] = 0.f;
  {                                      // exp-table preload (coalesced)
    const float* s1 = expd  + (b * NH + hq * 2) * NN;
    const float* s2 = expd2 + (b * NH + hq * 2) * NN;
    *(f32x4*)(ed_l + t * 4) = *(const f32x4*)(s1 + t * 4);
    *(f32x4*)(e2_l + t * 4) = *(const f32x4*)(s2 + t * 4);
  }
  #pragma unroll
  for (int k = 0; k < 2; k++){
    const int i = t + k * 512;
    mask_l[(i >> 5) * 33 + (i & 31)] = Aw[(b * NN + n0 + (i >> 5)) * 32 + (i & 31)];
  }
  __syncthreads();

  const int hb = (b * NH + h) * NN;
  const float Es  = exps [hb + n0 + rg * 16 + l15];
  const float Es2 = exps2[hb + n0 + rg * 16 + l15];
  const unsigned short* pb = hT + (size_t)(b * NH + h) * 65536 + l15 * 32 + quad * 8;
  const float* edh = ed_l + hl * NN + quad * 8;
  const float* e2h = e2_l + hl * NN + quad * 8;
  const unsigned* maskp = mask_l + (rg * 16 + l15) * 33;
  const int c0 = mh * 16;

  U8 pan[4];
  #pragma unroll
  for (int ss = 0; ss < 4; ss++)
    pan[ss].u = *(const u16x8*)(pb + (size_t)c0 * 2048 + ss * 512);

  f32x4 acc[4] = {};
  float lp = 0.f;

  for (int cc = 0; cc < 16; cc++){
    const int c = c0 + cc;
    const unsigned am = maskp[c] >> (quad * 8);
    float pv[8];
    #pragma unroll
    for (int g2 = 0; g2 < 2; g2++){
      f32x4 dv = *(const f32x4*)(edh + c * 32 + g2 * 4);
      f32x4 gv = *(const f32x4*)(e2h + c * 32 + g2 * 4);
      #pragma unroll
      for (int jj = 0; jj < 4; jj++){
        float e = fmaxf(Es * dv[jj], Es2 * gv[jj]);
        pv[g2 * 4 + jj] = (am & (1u << (g2 * 4 + jj))) ? e : 0.f;
      }
    }
    lp += ((pv[0] + pv[1]) + (pv[2] + pv[3])) + ((pv[4] + pv[5]) + (pv[6] + pv[7]));
    U8 pk;
    #pragma unroll
    for (int r = 0; r < 4; r++) pk.w[r] = pack_bf16(pv[2 * r], pv[2 * r + 1]);
    #pragma unroll
    for (int ss = 0; ss < 4; ss++)
      acc[ss] = __builtin_amdgcn_mfma_f32_16x16x32_bf16(pk.b, pan[ss].b, acc[ss], 0, 0, 0);
    if (cc + 1 < 16){
      #pragma unroll
      for (int ss = 0; ss < 4; ss++)
        pan[ss].u = *(const u16x8*)(pb + (size_t)(c + 1) * 2048 + ss * 512);
    }
  }

  // lane's lp = row l15's partial over this quad's cols; reduce quads + m-halves
  lp += __shfl_xor(lp, 16);
  lp += __shfl_xor(lp, 32);
  if (lane < 16) atomicAdd(&l_l[(w & 3) * 16 + lane], lp);
  __syncthreads();

  // normalize (1/8 folded) * mz, merge heads via global atomics
  const float* mzp = mz + b * NN + n0 + rg * 16;
  #pragma unroll
  for (int i = 0; i < 4; i++){
    const int row = quad * 4 + i;
    const float invm = (0.125f / l_l[(w & 3) * 16 + row]) * mzp[row];
    float* op = out + (size_t)(b * NN + n0 + rg * 16 + row) * FO + l15;
    #pragma unroll
    for (int ss = 0; ss < 4; ss++)
      atomicAdd(op + ss * 16, acc[ss][i] * invm);
  }
}

extern "C" void kernel_launch(void* const* d_in, const int* in_sizes, int n_in,
                              void* d_out, int out_size, void* d_ws, size_t ws_size,
                              hipStream_t stream)
{
  (void)in_sizes; (void)n_in; (void)out_size; (void)ws_size;
  const float* x    = (const float*)d_in[0];
  const int*   A    = (const int*)d_in[1];
  const float* mz   = (const float*)d_in[2];
  const float* e_at = (const float*)d_in[4];
  const float* Np   = (const float*)d_in[5];
  const float* w    = (const float*)d_in[6];
  const float* asrc = (const float*)d_in[7];
  const float* adst = (const float*)d_in[8];
  const float* bias = (const float*)d_in[9];
  float* out = (float*)d_out;

  char* ws = (char*)d_ws;
  unsigned short* wfrag = (unsigned short*)ws;                     // 256 KB
  unsigned short* hT    = (unsigned short*)(ws + 262144);          // 8 MB
  float* exps  = (float*)(ws + 8650752);                           // 256 KB
  float* exps2 = (float*)(ws + 8912896);                           // 256 KB
  float* expd  = (float*)(ws + 9175040);                           // 256 KB
  float* expd2 = (float*)(ws + 9437184);                           // 256 KB
  unsigned long long* Abits = (unsigned long long*)(ws + 9699328); // 1 MB

  stage0<<<dim3(1024), dim3(256), 0, stream>>>(w, A, bias, mz, wfrag, Abits, out);
  stageA<<<dim3(64, 8), dim3(512), 0, stream>>>(x, e_at, Np, wfrag, asrc, adst,
                                                hT, exps, exps2, expd, expd2);
  stageB<<<dim3(1024), dim3(512), 0, stream>>>((const unsigned*)Abits, hT,
                                               exps, exps2, expd, expd2,
                                               mz, out);
}